// Round 9
// baseline (172.946 us; speedup 1.0000x reference)
//
#include <hip/hip_runtime.h>

typedef __bf16 bf16;
typedef __bf16 bf16x4 __attribute__((ext_vector_type(4)));
typedef __bf16 bf16x8 __attribute__((ext_vector_type(8)));
typedef float  f32x2  __attribute__((ext_vector_type(2)));
typedef float  f32x4  __attribute__((ext_vector_type(4)));

#define HH 256
#define WW 256
#define NB 2
#define NC 64
#define NS 65536
#define EX 258      // extended conv grid: real coords -1..256, stored +1
#define NHEAD 4
#define DH 16
#define NSTRIPE 8
#define ACCSZ 2304  // per stripe: dots 2048 + qss 128 + kss 128

// ws layout (bytes)
#define OFF_CEXT   0ul                 // 2*258*258*64*2 = 17040384
#define OFF_KV     17040384ul          // kvT [b][s][c] bf16: 2*65536*64*2 = 16777216
#define OFF_WPK    33817600ul          // 73728
#define OFF_ACC    33891328ul          // 8*2304*4 = 73728

// ---------------- K0w: pack weights to A-frag layout + zero accums ---------
__global__ void k0w(const float* __restrict__ wgt, bf16* __restrict__ wpk,
                    float* __restrict__ accums) {
    int t = blockIdx.x * 256 + threadIdx.x;
    if (t < 9 * 2 * 4 * 64) {
        int L   = t & 63;
        int mtg = (t >> 6) & 3;
        int kc  = (t >> 8) & 1;
        int tap = t >> 9;
        int o  = mtg * 16 + (L & 15);
        int cb = kc * 32 + (L >> 4) * 8;
        bf16x8 vv;
        #pragma unroll
        for (int j = 0; j < 8; j++)
            vv[j] = (bf16)wgt[(o * 64 + (cb + j)) * 9 + tap];
        *(bf16x8*)(wpk + t * 8) = vv;
    }
    int z = t - 9 * 2 * 4 * 64;
    if (z >= 0 && z < NSTRIPE * ACCSZ) accums[z] = 0.0f;
}

// ---------------- K1: 3x3 conv, 3-row tiles for 3 blocks/CU ----------------
// tile = 64 out-ch x 3 rows x 64 cols; staging halo 5 rows.
// LDS = 5*68*72*2 = 48960 B -> 3 blocks/CU (146880 <= 163840).
// grid (5, 86, 2) = 860 blocks -> all 256 CUs covered (vs 215 at 6-row).
// __launch_bounds__(256,3) caps VGPR at 170 (afrag 144 + acc 16 + addr).
__global__ __launch_bounds__(256, 3) void k1_conv(const float* __restrict__ clone,
                                                  const bf16* __restrict__ wpk,
                                                  bf16* __restrict__ cext) {
    const int Xt = blockIdx.x;   // 0..4
    const int Yt = blockIdx.y;   // 0..85  (86*3 = 258 exactly)
    const int b  = blockIdx.z;
    const int t  = threadIdx.x;
    const int L  = t & 63;
    const int wv = t >> 6;
    const int mpair = wv >> 1;
    const int npair = wv & 1;

    extern __shared__ bf16 tile[];       // [5 rows][68 cols][c pitch 72]

    bf16x8 afrag[2][9][2];
    #pragma unroll
    for (int mt = 0; mt < 2; mt++)
        #pragma unroll
        for (int tap = 0; tap < 9; tap++)
            #pragma unroll
            for (int kc = 0; kc < 2; kc++) {
                int idx = ((tap * 2 + kc) * 4 + (mpair * 2 + mt)) * 64 + L;
                afrag[mt][tap][kc] = *(const bf16x8*)(wpk + idx * 8);
            }

    // stage: rows Yt*3-2..+2 (5), x = Xt*64-4..+63 (68 cols, 4-aligned), 64 ch.
    for (int u = t; u < 1360; u += 256) {
        int xq = u % 17;
        int rc = u / 17;
        int cg = rc & 15;
        int r  = rc >> 4;
        int y  = Yt * 3 - 2 + r;
        int xg0 = Xt * 64 - 4 + xq * 4;
        int c0 = cg * 4;
        f32x4 f[4];
        bool yin = (y >= 0) && (y < HH);
        if (yin && xg0 >= 0 && xg0 + 3 < WW) {
            #pragma unroll
            for (int i = 0; i < 4; i++)
                f[i] = *(const f32x4*)(clone + ((size_t)(b * NC + c0 + i) * HH + y) * WW + xg0);
        } else {
            #pragma unroll
            for (int i = 0; i < 4; i++)
                #pragma unroll
                for (int e = 0; e < 4; e++) {
                    int xg = xg0 + e;
                    f[i][e] = (yin && xg >= 0 && xg < WW)
                            ? clone[((size_t)(b * NC + c0 + i) * HH + y) * WW + xg] : 0.0f;
                }
        }
        #pragma unroll
        for (int e = 0; e < 4; e++) {
            bf16x4 h;
            #pragma unroll
            for (int i = 0; i < 4; i++) h[i] = (bf16)f[i][e];
            *(bf16x4*)(tile + (r * 68 + xq * 4 + e) * 72 + c0) = h;
        }
    }
    __syncthreads();

    const int nbase = Xt * 64 + npair * 32;
    const f32x4 zero4 = {0.0f, 0.0f, 0.0f, 0.0f};
    for (int Yi = 0; Yi < 3; Yi++) {
        f32x4 acc[2][2];
        acc[0][0] = zero4; acc[0][1] = zero4; acc[1][0] = zero4; acc[1][1] = zero4;
        #pragma unroll
        for (int tap = 0; tap < 9; tap++) {
            const int ky = tap / 3 - 1;
            const int kx = tap % 3 - 1;
            const int r = Yi + 1 + ky;
            #pragma unroll
            for (int kc = 0; kc < 2; kc++) {
                const int cb = kc * 32 + (L >> 4) * 8;
                #pragma unroll
                for (int nt = 0; nt < 2; nt++) {
                    if (nbase + nt * 16 < EX) {   // wave-uniform skip of dead N-tiles
                        const int col = npair * 32 + nt * 16 + (L & 15) + kx + 3;
                        bf16x8 bfrag = *(const bf16x8*)(tile + (r * 68 + col) * 72 + cb);
                        #pragma unroll
                        for (int mt = 0; mt < 2; mt++)
                            acc[mt][nt] = __builtin_amdgcn_mfma_f32_16x16x32_bf16(
                                afrag[mt][tap][kc], bfrag, acc[mt][nt], 0, 0, 0);
                    }
                }
            }
        }
        int Yp = Yt * 3 + Yi;    // max 85*3+2 = 257 < 258
        #pragma unroll
        for (int mt = 0; mt < 2; mt++)
            #pragma unroll
            for (int nt = 0; nt < 2; nt++) {
                int Xp = Xt * 64 + npair * 32 + nt * 16 + (L & 15);
                if (Xp < EX) {
                    int o = mpair * 32 + mt * 16 + (L >> 4) * 4;
                    bf16x4 st;
                    #pragma unroll
                    for (int rg = 0; rg < 4; rg++) st[rg] = (bf16)acc[mt][nt][rg];
                    *(bf16x4*)(cext + ((((size_t)b * EX + Yp) * EX + Xp) << 6) + o) = st;
                }
            }
    }
}

// ---------------- K2: fused gather + dots, 64-px strips (R8 verified) ------
__global__ __launch_bounds__(256) void k2_gd(const float* __restrict__ uu,
                                             const float* __restrict__ vv,
                                             const float* __restrict__ x,
                                             const bf16* __restrict__ cext,
                                             bf16* __restrict__ kvT,
                                             float* __restrict__ accums) {
    const int bx = blockIdx.x;                     // 0..1023
    const int b  = blockIdx.z;
    const int strip = (bx & 7) * 128 + (bx >> 3);  // bijective (1024 % 8 == 0)
    const int t = threadIdx.x;
    const int px = t >> 2;                         // 0..63
    const int q4 = t & 3;
    const int hw = strip * 64 + px;
    const int idx = b * NS + hw;
    const int hy = hw >> 8;
    const int wx = hw & 255;

    __shared__ bf16 tile[64][68];                  // [s_local][ch], pitch 68

    // ---- gather phase (verified algebra) ----
    float fv = vv[idx];
    float fu = uu[idx];
    float py_f = (float)hy + fv;
    float px_f = (float)wx + fu;
    float fy = floorf(py_f);
    float fx = floorf(px_f);
    float ay = py_f - fy;
    float ax = px_f - fx;
    int ys = (int)fy + 1;
    int xs = (int)fx + 1;
    float w00 = (1.0f - ay) * (1.0f - ax);
    float w01 = (1.0f - ay) * ax;
    float w10 = ay * (1.0f - ax);
    float w11 = ay * ax;
    bool y0i = (ys >= 0) && (ys < EX);
    bool y1i = (ys + 1 >= 0) && (ys + 1 < EX);
    bool x0i = (xs >= 0) && (xs < EX);
    bool x1i = (xs + 1 >= 0) && (xs + 1 < EX);
    if (!y0i) { w00 = 0.0f; w01 = 0.0f; }
    if (!y1i) { w10 = 0.0f; w11 = 0.0f; }
    if (!x0i) { w00 = 0.0f; w10 = 0.0f; }
    if (!x1i) { w01 = 0.0f; w11 = 0.0f; }
    int y0c = ys < 0 ? 0 : (ys > EX - 1 ? EX - 1 : ys);
    int y1c = ys + 1 < 0 ? 0 : (ys + 1 > EX - 1 ? EX - 1 : ys + 1);
    int x0c = xs < 0 ? 0 : (xs > EX - 1 ? EX - 1 : xs);
    int x1c = xs + 1 < 0 ? 0 : (xs + 1 > EX - 1 ? EX - 1 : xs + 1);
    const bf16* pb = cext + (((size_t)b * EX * EX) << 6);
    size_t i00 = ((size_t)(y0c * EX + x0c)) << 6;
    size_t i01 = ((size_t)(y0c * EX + x1c)) << 6;
    size_t i10 = ((size_t)(y1c * EX + x0c)) << 6;
    size_t i11 = ((size_t)(y1c * EX + x1c)) << 6;
    const int c0 = q4 * 16;
    bf16* kvp = kvT + ((size_t)(b * NS + hw)) * 64 + c0;   // 16B-aligned
    #pragma unroll
    for (int g = 0; g < 2; g++) {
        int cg = c0 + g * 8;
        bf16x8 c00 = *(const bf16x8*)(pb + i00 + cg);
        bf16x8 c01 = *(const bf16x8*)(pb + i01 + cg);
        bf16x8 c10 = *(const bf16x8*)(pb + i10 + cg);
        bf16x8 c11 = *(const bf16x8*)(pb + i11 + cg);
        bf16x4 lo, hi;
        bf16x8 sv;
        #pragma unroll
        for (int j = 0; j < 8; j++) {
            float val = w00 * (float)c00[j] + w01 * (float)c01[j]
                      + w10 * (float)c10[j] + w11 * (float)c11[j];
            bf16 hv = (bf16)val;
            sv[j] = hv;
            if (j < 4) lo[j] = hv; else hi[j - 4] = hv;
        }
        *(bf16x8*)(kvp + g * 8) = sv;                      // dense 16B store
        *(bf16x4*)(&tile[px][cg])     = lo;
        *(bf16x4*)(&tile[px][cg + 4]) = hi;
    }
    __syncthreads();

    // ---- dots phase: wave = head (2 MFMA k-iters over 64 s) ----
    const int L  = t & 63;
    const int h  = t >> 6;
    const int row = L & 15;
    const int kg  = L >> 4;
    const int bh = b * NHEAD + h;
    const float* qb = x + ((size_t)(b * NC + h * DH + row)) * NS + strip * 64;
    f32x4 acc = {0.0f, 0.0f, 0.0f, 0.0f};
    float qp = 0.0f, kp = 0.0f;
    #pragma unroll
    for (int it = 0; it < 2; it++) {
        const int s = it * 32 + kg * 8;
        f32x4 q0 = *(const f32x4*)(qb + s);
        f32x4 q1 = *(const f32x4*)(qb + s + 4);
        bf16x8 qa, ka;
        #pragma unroll
        for (int j = 0; j < 4; j++) {
            qa[j]     = (bf16)q0[j];
            qa[j + 4] = (bf16)q1[j];
        }
        #pragma unroll
        for (int j = 0; j < 8; j++) ka[j] = tile[s + j][h * DH + row];
        qp += q0[0]*q0[0] + q0[1]*q0[1] + q0[2]*q0[2] + q0[3]*q0[3]
            + q1[0]*q1[0] + q1[1]*q1[1] + q1[2]*q1[2] + q1[3]*q1[3];
        #pragma unroll
        for (int j = 0; j < 8; j++) {
            float kf = (float)ka[j];
            kp += kf * kf;
        }
        acc = __builtin_amdgcn_mfma_f32_16x16x32_bf16(qa, ka, acc, 0, 0, 0);
    }
    float* astripe = accums + (bx & 7) * ACCSZ;
    #pragma unroll
    for (int rg = 0; rg < 4; rg++)
        atomicAdd(astripe + bh * 256 + (kg * 4 + rg) * 16 + row, acc[rg]);
    qp += __shfl_xor(qp, 16); qp += __shfl_xor(qp, 32);
    kp += __shfl_xor(kp, 16); kp += __shfl_xor(kp, 32);
    if (kg == 0) {
        atomicAdd(astripe + 2048 + bh * 16 + row, qp);
        atomicAdd(astripe + 2176 + bh * 16 + row, kp);
    }
}

// ---------------- K5: softmax (redundant per block) + out = attn @ kv ------
// (R8 verified: 1024 blocks x 4 waves = 16 waves/CU; f32x2 per-thread tile)
__global__ __launch_bounds__(256) void k5_out(const bf16* __restrict__ kvT,
                                              const float* __restrict__ accums,
                                              const float* __restrict__ temp,
                                              float* __restrict__ out) {
    const int ci = blockIdx.x;  // 0..127 (512 s per block)
    const int h  = blockIdx.y;
    const int b  = blockIdx.z;
    const int t  = threadIdx.x;
    const int bh = b * NHEAD + h;
    __shared__ float l[256];
    __shared__ float a[256];
    {
        int i = t >> 4, j = t & 15;
        float dsum = 0.0f, q2 = 0.0f, k2 = 0.0f;
        #pragma unroll
        for (int st = 0; st < NSTRIPE; st++) {
            dsum += accums[st * ACCSZ + bh * 256 + t];
            q2   += accums[st * ACCSZ + 2048 + bh * 16 + i];
            k2   += accums[st * ACCSZ + 2176 + bh * 16 + j];
        }
        float qn = fmaxf(sqrtf(q2), 1e-12f);
        float kn = fmaxf(sqrtf(k2), 1e-12f);
        float logit = dsum / (qn * kn) * temp[h];
        l[t] = logit;
        __syncthreads();
        float mx = -1e30f;
        #pragma unroll
        for (int jj = 0; jj < 16; jj++) mx = fmaxf(mx, l[i * 16 + jj]);
        float sum = 0.0f;
        #pragma unroll
        for (int jj = 0; jj < 16; jj++) sum += expf(l[i * 16 + jj] - mx);
        a[t] = expf(logit - mx) / sum;
        __syncthreads();
    }
    const int s = (ci * 256 + t) * 2;
    const bf16* kvb = kvT + ((size_t)(b * NS + s)) * 64 + h * DH;
    f32x2 kf[16];   // kf[j] = channel j over the 2 px (e)
    #pragma unroll
    for (int e = 0; e < 2; e++) {
        bf16x8 k0 = *(const bf16x8*)(kvb + e * 64);
        bf16x8 k1 = *(const bf16x8*)(kvb + e * 64 + 8);
        #pragma unroll
        for (int j = 0; j < 8; j++) {
            kf[j][e]     = (float)k0[j];
            kf[8 + j][e] = (float)k1[j];
        }
    }
    float* ob = out + ((size_t)(b * NC + h * DH)) * NS + s;
    #pragma unroll
    for (int i = 0; i < 16; i++) {
        f32x2 o = {0.0f, 0.0f};
        #pragma unroll
        for (int j = 0; j < 16; j++)
            o += a[i * 16 + j] * kf[j];
        *(f32x2*)(ob + (size_t)i * NS) = o;
    }
}

extern "C" void kernel_launch(void* const* d_in, const int* in_sizes, int n_in,
                              void* d_out, int out_size, void* d_ws, size_t ws_size,
                              hipStream_t stream) {
    const float* clone = (const float*)d_in[0];
    const float* x     = (const float*)d_in[1];
    const float* u     = (const float*)d_in[2];
    const float* v     = (const float*)d_in[3];
    const float* wgt   = (const float*)d_in[4];
    const float* temp  = (const float*)d_in[5];
    float* out = (float*)d_out;

    char* ws = (char*)d_ws;
    bf16*  cext   = (bf16*) (ws + OFF_CEXT);
    bf16*  kvT    = (bf16*) (ws + OFF_KV);
    bf16*  wpk    = (bf16*) (ws + OFF_WPK);
    float* accums = (float*)(ws + OFF_ACC);

    static bool attr_set = false;
    if (!attr_set) {
        hipFuncSetAttribute((const void*)k1_conv,
                            hipFuncAttributeMaxDynamicSharedMemorySize, 48960);
        attr_set = true;
    }

    k0w<<<90, 256, 0, stream>>>(wgt, wpk, accums);
    k1_conv<<<dim3(5, 86, 2), 256, 48960, stream>>>(clone, wpk, cext);
    k2_gd<<<dim3(1024, 1, 2), 256, 0, stream>>>(u, v, x, cext, kvT, accums);
    k5_out<<<dim3(128, 4, 2), 256, 0, stream>>>(kvT, accums, temp, out);
}

// Round 10
// 165.368 us; speedup vs baseline: 1.0458x; 1.0458x over previous
//
#include <hip/hip_runtime.h>

typedef __bf16 bf16;
typedef __bf16 bf16x4 __attribute__((ext_vector_type(4)));
typedef __bf16 bf16x8 __attribute__((ext_vector_type(8)));
typedef float  f32x2  __attribute__((ext_vector_type(2)));
typedef float  f32x4  __attribute__((ext_vector_type(4)));

#define HH 256
#define WW 256
#define NB 2
#define NC 64
#define NS 65536
#define EX 258      // extended conv grid: real coords -1..256, stored +1
#define NHEAD 4
#define DH 16
#define NSTRIPE 8
#define ACCSZ 2304  // per stripe: dots 2048 + qss 128 + kss 128

// ws layout (bytes)
#define OFF_CEXT   0ul                 // 2*258*258*64*2 = 17040384
#define OFF_KV     17040384ul          // kvT [b][s][c] bf16: 2*65536*64*2 = 16777216
#define OFF_WPK    33817600ul          // 73728
#define OFF_ACC    33891328ul          // 8*2304*4 = 73728

// ---------------- K0w: pack weights to A-frag layout + zero accums ---------
__global__ void k0w(const float* __restrict__ wgt, bf16* __restrict__ wpk,
                    float* __restrict__ accums) {
    int t = blockIdx.x * 256 + threadIdx.x;
    if (t < 9 * 2 * 4 * 64) {
        int L   = t & 63;
        int mtg = (t >> 6) & 3;
        int kc  = (t >> 8) & 1;
        int tap = t >> 9;
        int o  = mtg * 16 + (L & 15);
        int cb = kc * 32 + (L >> 4) * 8;
        bf16x8 vv;
        #pragma unroll
        for (int j = 0; j < 8; j++)
            vv[j] = (bf16)wgt[(o * 64 + (cb + j)) * 9 + tap];
        *(bf16x8*)(wpk + t * 8) = vv;
    }
    int z = t - 9 * 2 * 4 * 64;
    if (z >= 0 && z < NSTRIPE * ACCSZ) accums[z] = 0.0f;
}

// ---------------- K1: 3x3 conv, 8-wave m-split for 2x occupancy ------------
// 512 thr = 8 waves; wave = (mtg 0..3, npair 0..1). Each wave holds only
// afrag[9][2] = 72 VGPR (half of the 4-wave version) -> fits the 128-VGPR
// cap of __launch_bounds__(512,4) with NO spill (R9's regression was the
// 256,3 cap spilling the 144-VGPR afrag to scratch: VGPR_Count 84,
// WRITE_SIZE 30 MB vs 17 ideal).
// Tile = 64 out-ch x 6 rows x 64 cols; LDS 78336 -> 2 blocks/CU
// -> 16 waves/CU (2x the R8 4-wave version). Same MFMA count, same stores.
__global__ __launch_bounds__(512, 4) void k1_conv(const float* __restrict__ clone,
                                                  const bf16* __restrict__ wpk,
                                                  bf16* __restrict__ cext) {
    const int Xt = blockIdx.x;   // 0..4
    const int Yt = blockIdx.y;   // 0..42  (43*6 = 258 exactly)
    const int b  = blockIdx.z;
    const int t  = threadIdx.x;  // 0..511
    const int L  = t & 63;
    const int wv = t >> 6;       // 0..7
    const int mtg   = wv >> 1;   // 0..3 (out-ch group of 16)
    const int npair = wv & 1;

    extern __shared__ bf16 tile[];       // [8 rows][68 cols][c pitch 72]

    // stage: rows Yt*6-2..+5 (8), x = Xt*64-4..+63 (68 cols, 4-aligned), 64 ch.
    for (int u = t; u < 2176; u += 512) {
        int xq = u % 17;
        int rc = u / 17;
        int cg = rc & 15;
        int r  = rc >> 4;
        int y  = Yt * 6 - 2 + r;
        int xg0 = Xt * 64 - 4 + xq * 4;
        int c0 = cg * 4;
        f32x4 f[4];
        bool yin = (y >= 0) && (y < HH);
        if (yin && xg0 >= 0 && xg0 + 3 < WW) {
            #pragma unroll
            for (int i = 0; i < 4; i++)
                f[i] = *(const f32x4*)(clone + ((size_t)(b * NC + c0 + i) * HH + y) * WW + xg0);
        } else {
            #pragma unroll
            for (int i = 0; i < 4; i++)
                #pragma unroll
                for (int e = 0; e < 4; e++) {
                    int xg = xg0 + e;
                    f[i][e] = (yin && xg >= 0 && xg < WW)
                            ? clone[((size_t)(b * NC + c0 + i) * HH + y) * WW + xg] : 0.0f;
                }
        }
        #pragma unroll
        for (int e = 0; e < 4; e++) {
            bf16x4 h;
            #pragma unroll
            for (int i = 0; i < 4; i++) h[i] = (bf16)f[i][e];
            *(bf16x4*)(tile + (r * 68 + xq * 4 + e) * 72 + c0) = h;
        }
    }

    // weight A-fragments loaded AFTER staging (keeps staging live-set small)
    bf16x8 afrag[9][2];
    #pragma unroll
    for (int tap = 0; tap < 9; tap++)
        #pragma unroll
        for (int kc = 0; kc < 2; kc++) {
            int idx = ((tap * 2 + kc) * 4 + mtg) * 64 + L;
            afrag[tap][kc] = *(const bf16x8*)(wpk + idx * 8);
        }
    __syncthreads();

    const int nbase = Xt * 64 + npair * 32;
    const f32x4 zero4 = {0.0f, 0.0f, 0.0f, 0.0f};
    for (int Yi = 0; Yi < 6; Yi++) {
        f32x4 acc[2];
        acc[0] = zero4; acc[1] = zero4;
        #pragma unroll
        for (int tap = 0; tap < 9; tap++) {
            const int ky = tap / 3 - 1;
            const int kx = tap % 3 - 1;
            const int r = Yi + 1 + ky;
            #pragma unroll
            for (int kc = 0; kc < 2; kc++) {
                const int cb = kc * 32 + (L >> 4) * 8;
                #pragma unroll
                for (int nt = 0; nt < 2; nt++) {
                    if (nbase + nt * 16 < EX) {   // wave-uniform skip of dead N-tiles
                        const int col = npair * 32 + nt * 16 + (L & 15) + kx + 3;
                        bf16x8 bfrag = *(const bf16x8*)(tile + (r * 68 + col) * 72 + cb);
                        acc[nt] = __builtin_amdgcn_mfma_f32_16x16x32_bf16(
                            afrag[tap][kc], bfrag, acc[nt], 0, 0, 0);
                    }
                }
            }
        }
        int Yp = Yt * 6 + Yi;
        #pragma unroll
        for (int nt = 0; nt < 2; nt++) {
            int Xp = Xt * 64 + npair * 32 + nt * 16 + (L & 15);
            if (Xp < EX) {
                int o = mtg * 16 + (L >> 4) * 4;
                bf16x4 st;
                #pragma unroll
                for (int rg = 0; rg < 4; rg++) st[rg] = (bf16)acc[nt][rg];
                *(bf16x4*)(cext + ((((size_t)b * EX + Yp) * EX + Xp) << 6) + o) = st;
            }
        }
    }
}

// ---------------- K2: fused gather + dots, 64-px strips (R8 verified) ------
__global__ __launch_bounds__(256) void k2_gd(const float* __restrict__ uu,
                                             const float* __restrict__ vv,
                                             const float* __restrict__ x,
                                             const bf16* __restrict__ cext,
                                             bf16* __restrict__ kvT,
                                             float* __restrict__ accums) {
    const int bx = blockIdx.x;                     // 0..1023
    const int b  = blockIdx.z;
    const int strip = (bx & 7) * 128 + (bx >> 3);  // bijective (1024 % 8 == 0)
    const int t = threadIdx.x;
    const int px = t >> 2;                         // 0..63
    const int q4 = t & 3;
    const int hw = strip * 64 + px;
    const int idx = b * NS + hw;
    const int hy = hw >> 8;
    const int wx = hw & 255;

    __shared__ bf16 tile[64][68];                  // [s_local][ch], pitch 68

    // ---- gather phase (verified algebra) ----
    float fv = vv[idx];
    float fu = uu[idx];
    float py_f = (float)hy + fv;
    float px_f = (float)wx + fu;
    float fy = floorf(py_f);
    float fx = floorf(px_f);
    float ay = py_f - fy;
    float ax = px_f - fx;
    int ys = (int)fy + 1;
    int xs = (int)fx + 1;
    float w00 = (1.0f - ay) * (1.0f - ax);
    float w01 = (1.0f - ay) * ax;
    float w10 = ay * (1.0f - ax);
    float w11 = ay * ax;
    bool y0i = (ys >= 0) && (ys < EX);
    bool y1i = (ys + 1 >= 0) && (ys + 1 < EX);
    bool x0i = (xs >= 0) && (xs < EX);
    bool x1i = (xs + 1 >= 0) && (xs + 1 < EX);
    if (!y0i) { w00 = 0.0f; w01 = 0.0f; }
    if (!y1i) { w10 = 0.0f; w11 = 0.0f; }
    if (!x0i) { w00 = 0.0f; w10 = 0.0f; }
    if (!x1i) { w01 = 0.0f; w11 = 0.0f; }
    int y0c = ys < 0 ? 0 : (ys > EX - 1 ? EX - 1 : ys);
    int y1c = ys + 1 < 0 ? 0 : (ys + 1 > EX - 1 ? EX - 1 : ys + 1);
    int x0c = xs < 0 ? 0 : (xs > EX - 1 ? EX - 1 : xs);
    int x1c = xs + 1 < 0 ? 0 : (xs + 1 > EX - 1 ? EX - 1 : xs + 1);
    const bf16* pb = cext + (((size_t)b * EX * EX) << 6);
    size_t i00 = ((size_t)(y0c * EX + x0c)) << 6;
    size_t i01 = ((size_t)(y0c * EX + x1c)) << 6;
    size_t i10 = ((size_t)(y1c * EX + x0c)) << 6;
    size_t i11 = ((size_t)(y1c * EX + x1c)) << 6;
    const int c0 = q4 * 16;
    bf16* kvp = kvT + ((size_t)(b * NS + hw)) * 64 + c0;   // 16B-aligned
    #pragma unroll
    for (int g = 0; g < 2; g++) {
        int cg = c0 + g * 8;
        bf16x8 c00 = *(const bf16x8*)(pb + i00 + cg);
        bf16x8 c01 = *(const bf16x8*)(pb + i01 + cg);
        bf16x8 c10 = *(const bf16x8*)(pb + i10 + cg);
        bf16x8 c11 = *(const bf16x8*)(pb + i11 + cg);
        bf16x4 lo, hi;
        bf16x8 sv;
        #pragma unroll
        for (int j = 0; j < 8; j++) {
            float val = w00 * (float)c00[j] + w01 * (float)c01[j]
                      + w10 * (float)c10[j] + w11 * (float)c11[j];
            bf16 hv = (bf16)val;
            sv[j] = hv;
            if (j < 4) lo[j] = hv; else hi[j - 4] = hv;
        }
        *(bf16x8*)(kvp + g * 8) = sv;                      // dense 16B store
        *(bf16x4*)(&tile[px][cg])     = lo;
        *(bf16x4*)(&tile[px][cg + 4]) = hi;
    }
    __syncthreads();

    // ---- dots phase: wave = head (2 MFMA k-iters over 64 s) ----
    const int L  = t & 63;
    const int h  = t >> 6;
    const int row = L & 15;
    const int kg  = L >> 4;
    const int bh = b * NHEAD + h;
    const float* qb = x + ((size_t)(b * NC + h * DH + row)) * NS + strip * 64;
    f32x4 acc = {0.0f, 0.0f, 0.0f, 0.0f};
    float qp = 0.0f, kp = 0.0f;
    #pragma unroll
    for (int it = 0; it < 2; it++) {
        const int s = it * 32 + kg * 8;
        f32x4 q0 = *(const f32x4*)(qb + s);
        f32x4 q1 = *(const f32x4*)(qb + s + 4);
        bf16x8 qa, ka;
        #pragma unroll
        for (int j = 0; j < 4; j++) {
            qa[j]     = (bf16)q0[j];
            qa[j + 4] = (bf16)q1[j];
        }
        #pragma unroll
        for (int j = 0; j < 8; j++) ka[j] = tile[s + j][h * DH + row];
        qp += q0[0]*q0[0] + q0[1]*q0[1] + q0[2]*q0[2] + q0[3]*q0[3]
            + q1[0]*q1[0] + q1[1]*q1[1] + q1[2]*q1[2] + q1[3]*q1[3];
        #pragma unroll
        for (int j = 0; j < 8; j++) {
            float kf = (float)ka[j];
            kp += kf * kf;
        }
        acc = __builtin_amdgcn_mfma_f32_16x16x32_bf16(qa, ka, acc, 0, 0, 0);
    }
    float* astripe = accums + (bx & 7) * ACCSZ;
    #pragma unroll
    for (int rg = 0; rg < 4; rg++)
        atomicAdd(astripe + bh * 256 + (kg * 4 + rg) * 16 + row, acc[rg]);
    qp += __shfl_xor(qp, 16); qp += __shfl_xor(qp, 32);
    kp += __shfl_xor(kp, 16); kp += __shfl_xor(kp, 32);
    if (kg == 0) {
        atomicAdd(astripe + 2048 + bh * 16 + row, qp);
        atomicAdd(astripe + 2176 + bh * 16 + row, kp);
    }
}

// ---------------- K5: softmax (redundant per block) + out = attn @ kv ------
// (R8 verified: 1024 blocks x 4 waves = 16 waves/CU; f32x2 per-thread tile)
__global__ __launch_bounds__(256) void k5_out(const bf16* __restrict__ kvT,
                                              const float* __restrict__ accums,
                                              const float* __restrict__ temp,
                                              float* __restrict__ out) {
    const int ci = blockIdx.x;  // 0..127 (512 s per block)
    const int h  = blockIdx.y;
    const int b  = blockIdx.z;
    const int t  = threadIdx.x;
    const int bh = b * NHEAD + h;
    __shared__ float l[256];
    __shared__ float a[256];
    {
        int i = t >> 4, j = t & 15;
        float dsum = 0.0f, q2 = 0.0f, k2 = 0.0f;
        #pragma unroll
        for (int st = 0; st < NSTRIPE; st++) {
            dsum += accums[st * ACCSZ + bh * 256 + t];
            q2   += accums[st * ACCSZ + 2048 + bh * 16 + i];
            k2   += accums[st * ACCSZ + 2176 + bh * 16 + j];
        }
        float qn = fmaxf(sqrtf(q2), 1e-12f);
        float kn = fmaxf(sqrtf(k2), 1e-12f);
        float logit = dsum / (qn * kn) * temp[h];
        l[t] = logit;
        __syncthreads();
        float mx = -1e30f;
        #pragma unroll
        for (int jj = 0; jj < 16; jj++) mx = fmaxf(mx, l[i * 16 + jj]);
        float sum = 0.0f;
        #pragma unroll
        for (int jj = 0; jj < 16; jj++) sum += expf(l[i * 16 + jj] - mx);
        a[t] = expf(logit - mx) / sum;
        __syncthreads();
    }
    const int s = (ci * 256 + t) * 2;
    const bf16* kvb = kvT + ((size_t)(b * NS + s)) * 64 + h * DH;
    f32x2 kf[16];   // kf[j] = channel j over the 2 px (e)
    #pragma unroll
    for (int e = 0; e < 2; e++) {
        bf16x8 k0 = *(const bf16x8*)(kvb + e * 64);
        bf16x8 k1 = *(const bf16x8*)(kvb + e * 64 + 8);
        #pragma unroll
        for (int j = 0; j < 8; j++) {
            kf[j][e]     = (float)k0[j];
            kf[8 + j][e] = (float)k1[j];
        }
    }
    float* ob = out + ((size_t)(b * NC + h * DH)) * NS + s;
    #pragma unroll
    for (int i = 0; i < 16; i++) {
        f32x2 o = {0.0f, 0.0f};
        #pragma unroll
        for (int j = 0; j < 16; j++)
            o += a[i * 16 + j] * kf[j];
        *(f32x2*)(ob + (size_t)i * NS) = o;
    }
}

extern "C" void kernel_launch(void* const* d_in, const int* in_sizes, int n_in,
                              void* d_out, int out_size, void* d_ws, size_t ws_size,
                              hipStream_t stream) {
    const float* clone = (const float*)d_in[0];
    const float* x     = (const float*)d_in[1];
    const float* u     = (const float*)d_in[2];
    const float* v     = (const float*)d_in[3];
    const float* wgt   = (const float*)d_in[4];
    const float* temp  = (const float*)d_in[5];
    float* out = (float*)d_out;

    char* ws = (char*)d_ws;
    bf16*  cext   = (bf16*) (ws + OFF_CEXT);
    bf16*  kvT    = (bf16*) (ws + OFF_KV);
    bf16*  wpk    = (bf16*) (ws + OFF_WPK);
    float* accums = (float*)(ws + OFF_ACC);

    static bool attr_set = false;
    if (!attr_set) {
        hipFuncSetAttribute((const void*)k1_conv,
                            hipFuncAttributeMaxDynamicSharedMemorySize, 78336);
        attr_set = true;
    }

    k0w<<<90, 256, 0, stream>>>(wgt, wpk, accums);
    k1_conv<<<dim3(5, 43, 2), 512, 78336, stream>>>(clone, wpk, cext);
    k2_gd<<<dim3(1024, 1, 2), 256, 0, stream>>>(u, v, x, cext, kvT, accums);
    k5_out<<<dim3(128, 4, 2), 256, 0, stream>>>(kvT, accums, temp, out);
}

// Round 11
// 157.648 us; speedup vs baseline: 1.0970x; 1.0490x over previous
//
#include <hip/hip_runtime.h>

typedef __bf16 bf16;
typedef __bf16 bf16x4 __attribute__((ext_vector_type(4)));
typedef __bf16 bf16x8 __attribute__((ext_vector_type(8)));
typedef float  f32x2  __attribute__((ext_vector_type(2)));
typedef float  f32x4  __attribute__((ext_vector_type(4)));

#define HH 256
#define WW 256
#define NB 2
#define NC 64
#define NS 65536
#define EX 258      // extended conv grid: real coords -1..256, stored +1
#define NHEAD 4
#define DH 16
#define NSTRIPE 8
#define ACCSZ 2304  // per stripe: dots 2048 + qss 128 + kss 128

// ws layout (bytes)
#define OFF_CEXT   0ul                 // 2*258*258*64*2 = 17040384
#define OFF_KV     17040384ul          // kvT [b][s][c] bf16: 2*65536*64*2 = 16777216
#define OFF_WPK    33817600ul          // 73728
#define OFF_ACC    33891328ul          // 8*2304*4 = 73728

// ---------------- K0w: pack weights to A-frag layout + zero accums ---------
__global__ void k0w(const float* __restrict__ wgt, bf16* __restrict__ wpk,
                    float* __restrict__ accums) {
    int t = blockIdx.x * 256 + threadIdx.x;
    if (t < 9 * 2 * 4 * 64) {
        int L   = t & 63;
        int mtg = (t >> 6) & 3;
        int kc  = (t >> 8) & 1;
        int tap = t >> 9;
        int o  = mtg * 16 + (L & 15);
        int cb = kc * 32 + (L >> 4) * 8;
        bf16x8 vv;
        #pragma unroll
        for (int j = 0; j < 8; j++)
            vv[j] = (bf16)wgt[(o * 64 + (cb + j)) * 9 + tap];
        *(bf16x8*)(wpk + t * 8) = vv;
    }
    int z = t - 9 * 2 * 4 * 64;
    if (z >= 0 && z < NSTRIPE * ACCSZ) accums[z] = 0.0f;
}

// ---------------- K1: 3x3 conv (R8-verified: 4 waves, 6-row tile) ----------
// R10 lesson: 8-wave m-split halved MFMA-per-ds_read (LDS traffic 2x) and
// regressed; this 4-wave form (each bfrag feeds 2 MFMAs) is the best verified.
__global__ __launch_bounds__(256, 2) void k1_conv(const float* __restrict__ clone,
                                                  const bf16* __restrict__ wpk,
                                                  bf16* __restrict__ cext) {
    const int Xt = blockIdx.x;   // 0..4
    const int Yt = blockIdx.y;   // 0..42  (43*6 = 258 exactly)
    const int b  = blockIdx.z;
    const int t  = threadIdx.x;
    const int L  = t & 63;
    const int wv = t >> 6;
    const int mpair = wv >> 1;
    const int npair = wv & 1;

    extern __shared__ bf16 tile[];       // [8 rows][68 cols][c pitch 72]

    bf16x8 afrag[2][9][2];
    #pragma unroll
    for (int mt = 0; mt < 2; mt++)
        #pragma unroll
        for (int tap = 0; tap < 9; tap++)
            #pragma unroll
            for (int kc = 0; kc < 2; kc++) {
                int idx = ((tap * 2 + kc) * 4 + (mpair * 2 + mt)) * 64 + L;
                afrag[mt][tap][kc] = *(const bf16x8*)(wpk + idx * 8);
            }

    for (int u = t; u < 2176; u += 256) {
        int xq = u % 17;
        int rc = u / 17;
        int cg = rc & 15;
        int r  = rc >> 4;
        int y  = Yt * 6 - 2 + r;
        int xg0 = Xt * 64 - 4 + xq * 4;
        int c0 = cg * 4;
        f32x4 f[4];
        bool yin = (y >= 0) && (y < HH);
        if (yin && xg0 >= 0 && xg0 + 3 < WW) {
            #pragma unroll
            for (int i = 0; i < 4; i++)
                f[i] = *(const f32x4*)(clone + ((size_t)(b * NC + c0 + i) * HH + y) * WW + xg0);
        } else {
            #pragma unroll
            for (int i = 0; i < 4; i++)
                #pragma unroll
                for (int e = 0; e < 4; e++) {
                    int xg = xg0 + e;
                    f[i][e] = (yin && xg >= 0 && xg < WW)
                            ? clone[((size_t)(b * NC + c0 + i) * HH + y) * WW + xg] : 0.0f;
                }
        }
        #pragma unroll
        for (int e = 0; e < 4; e++) {
            bf16x4 h;
            #pragma unroll
            for (int i = 0; i < 4; i++) h[i] = (bf16)f[i][e];
            *(bf16x4*)(tile + (r * 68 + xq * 4 + e) * 72 + c0) = h;
        }
    }
    __syncthreads();

    const int nbase = Xt * 64 + npair * 32;
    const f32x4 zero4 = {0.0f, 0.0f, 0.0f, 0.0f};
    for (int Yi = 0; Yi < 6; Yi++) {
        f32x4 acc[2][2];
        acc[0][0] = zero4; acc[0][1] = zero4; acc[1][0] = zero4; acc[1][1] = zero4;
        #pragma unroll
        for (int tap = 0; tap < 9; tap++) {
            const int ky = tap / 3 - 1;
            const int kx = tap % 3 - 1;
            const int r = Yi + 1 + ky;
            #pragma unroll
            for (int kc = 0; kc < 2; kc++) {
                const int cb = kc * 32 + (L >> 4) * 8;
                #pragma unroll
                for (int nt = 0; nt < 2; nt++) {
                    if (nbase + nt * 16 < EX) {   // wave-uniform skip of dead N-tiles
                        const int col = npair * 32 + nt * 16 + (L & 15) + kx + 3;
                        bf16x8 bfrag = *(const bf16x8*)(tile + (r * 68 + col) * 72 + cb);
                        #pragma unroll
                        for (int mt = 0; mt < 2; mt++)
                            acc[mt][nt] = __builtin_amdgcn_mfma_f32_16x16x32_bf16(
                                afrag[mt][tap][kc], bfrag, acc[mt][nt], 0, 0, 0);
                    }
                }
            }
        }
        int Yp = Yt * 6 + Yi;
        #pragma unroll
        for (int mt = 0; mt < 2; mt++)
            #pragma unroll
            for (int nt = 0; nt < 2; nt++) {
                int Xp = Xt * 64 + npair * 32 + nt * 16 + (L & 15);
                if (Xp < EX) {
                    int o = mpair * 32 + mt * 16 + (L >> 4) * 4;
                    bf16x4 st;
                    #pragma unroll
                    for (int rg = 0; rg < 4; rg++) st[rg] = (bf16)acc[mt][nt][rg];
                    *(bf16x4*)(cext + ((((size_t)b * EX + Yp) * EX + Xp) << 6) + o) = st;
                }
            }
    }
}

// ---------------- K2: fused gather + dots, 64-px strips (R8 verified) ------
__global__ __launch_bounds__(256) void k2_gd(const float* __restrict__ uu,
                                             const float* __restrict__ vv,
                                             const float* __restrict__ x,
                                             const bf16* __restrict__ cext,
                                             bf16* __restrict__ kvT,
                                             float* __restrict__ accums) {
    const int bx = blockIdx.x;                     // 0..1023
    const int b  = blockIdx.z;
    const int strip = (bx & 7) * 128 + (bx >> 3);  // bijective (1024 % 8 == 0)
    const int t = threadIdx.x;
    const int px = t >> 2;                         // 0..63
    const int q4 = t & 3;
    const int hw = strip * 64 + px;
    const int idx = b * NS + hw;
    const int hy = hw >> 8;
    const int wx = hw & 255;

    __shared__ bf16 tile[64][68];                  // [s_local][ch], pitch 68

    // ---- gather phase (verified algebra) ----
    float fv = vv[idx];
    float fu = uu[idx];
    float py_f = (float)hy + fv;
    float px_f = (float)wx + fu;
    float fy = floorf(py_f);
    float fx = floorf(px_f);
    float ay = py_f - fy;
    float ax = px_f - fx;
    int ys = (int)fy + 1;
    int xs = (int)fx + 1;
    float w00 = (1.0f - ay) * (1.0f - ax);
    float w01 = (1.0f - ay) * ax;
    float w10 = ay * (1.0f - ax);
    float w11 = ay * ax;
    bool y0i = (ys >= 0) && (ys < EX);
    bool y1i = (ys + 1 >= 0) && (ys + 1 < EX);
    bool x0i = (xs >= 0) && (xs < EX);
    bool x1i = (xs + 1 >= 0) && (xs + 1 < EX);
    if (!y0i) { w00 = 0.0f; w01 = 0.0f; }
    if (!y1i) { w10 = 0.0f; w11 = 0.0f; }
    if (!x0i) { w00 = 0.0f; w10 = 0.0f; }
    if (!x1i) { w01 = 0.0f; w11 = 0.0f; }
    int y0c = ys < 0 ? 0 : (ys > EX - 1 ? EX - 1 : ys);
    int y1c = ys + 1 < 0 ? 0 : (ys + 1 > EX - 1 ? EX - 1 : ys + 1);
    int x0c = xs < 0 ? 0 : (xs > EX - 1 ? EX - 1 : xs);
    int x1c = xs + 1 < 0 ? 0 : (xs + 1 > EX - 1 ? EX - 1 : xs + 1);
    const bf16* pb = cext + (((size_t)b * EX * EX) << 6);
    size_t i00 = ((size_t)(y0c * EX + x0c)) << 6;
    size_t i01 = ((size_t)(y0c * EX + x1c)) << 6;
    size_t i10 = ((size_t)(y1c * EX + x0c)) << 6;
    size_t i11 = ((size_t)(y1c * EX + x1c)) << 6;
    const int c0 = q4 * 16;
    bf16* kvp = kvT + ((size_t)(b * NS + hw)) * 64 + c0;   // 16B-aligned
    #pragma unroll
    for (int g = 0; g < 2; g++) {
        int cg = c0 + g * 8;
        bf16x8 c00 = *(const bf16x8*)(pb + i00 + cg);
        bf16x8 c01 = *(const bf16x8*)(pb + i01 + cg);
        bf16x8 c10 = *(const bf16x8*)(pb + i10 + cg);
        bf16x8 c11 = *(const bf16x8*)(pb + i11 + cg);
        bf16x4 lo, hi;
        bf16x8 sv;
        #pragma unroll
        for (int j = 0; j < 8; j++) {
            float val = w00 * (float)c00[j] + w01 * (float)c01[j]
                      + w10 * (float)c10[j] + w11 * (float)c11[j];
            bf16 hv = (bf16)val;
            sv[j] = hv;
            if (j < 4) lo[j] = hv; else hi[j - 4] = hv;
        }
        *(bf16x8*)(kvp + g * 8) = sv;                      // dense 16B store
        *(bf16x4*)(&tile[px][cg])     = lo;
        *(bf16x4*)(&tile[px][cg + 4]) = hi;
    }
    __syncthreads();

    // ---- dots phase: wave = head (2 MFMA k-iters over 64 s) ----
    const int L  = t & 63;
    const int h  = t >> 6;
    const int row = L & 15;
    const int kg  = L >> 4;
    const int bh = b * NHEAD + h;
    const float* qb = x + ((size_t)(b * NC + h * DH + row)) * NS + strip * 64;
    f32x4 acc = {0.0f, 0.0f, 0.0f, 0.0f};
    float qp = 0.0f, kp = 0.0f;
    #pragma unroll
    for (int it = 0; it < 2; it++) {
        const int s = it * 32 + kg * 8;
        f32x4 q0 = *(const f32x4*)(qb + s);
        f32x4 q1 = *(const f32x4*)(qb + s + 4);
        bf16x8 qa, ka;
        #pragma unroll
        for (int j = 0; j < 4; j++) {
            qa[j]     = (bf16)q0[j];
            qa[j + 4] = (bf16)q1[j];
        }
        #pragma unroll
        for (int j = 0; j < 8; j++) ka[j] = tile[s + j][h * DH + row];
        qp += q0[0]*q0[0] + q0[1]*q0[1] + q0[2]*q0[2] + q0[3]*q0[3]
            + q1[0]*q1[0] + q1[1]*q1[1] + q1[2]*q1[2] + q1[3]*q1[3];
        #pragma unroll
        for (int j = 0; j < 8; j++) {
            float kf = (float)ka[j];
            kp += kf * kf;
        }
        acc = __builtin_amdgcn_mfma_f32_16x16x32_bf16(qa, ka, acc, 0, 0, 0);
    }
    float* astripe = accums + (bx & 7) * ACCSZ;
    #pragma unroll
    for (int rg = 0; rg < 4; rg++)
        atomicAdd(astripe + bh * 256 + (kg * 4 + rg) * 16 + row, acc[rg]);
    qp += __shfl_xor(qp, 16); qp += __shfl_xor(qp, 32);
    kp += __shfl_xor(kp, 16); kp += __shfl_xor(kp, 32);
    if (kg == 0) {
        atomicAdd(astripe + 2048 + bh * 16 + row, qp);
        atomicAdd(astripe + 2176 + bh * 16 + row, kp);
    }
}

// ---------------- K5: softmax + out = attn @ kv via MFMA -------------------
// VALU FMA had a 17 us device floor (1.34G f32 FMAs at 157 TF); MFMA removes it.
// Per wave: A-frag hoisted once: k=0..15 holds attn_hi = bf16(a), k=16..31
// holds attn_lo = bf16(a - hi); B duplicates kv rows in both K-halves, so one
// mfma_16x16x32 computes hi@kv + lo@kv = f32-precision attn@kv (err ~2^-17).
// Fragment mapping verified by k2's refchecked dots: A[m=L&15][k=(L>>4)*8+j],
// B[k][n=L&15], D row=(L>>4)*4+r, col=L&15.
// XCD swizzle on ci aligns each XCD's kvT reads with the rows its k2 wrote.
__global__ __launch_bounds__(256) void k5_out(const bf16* __restrict__ kvT,
                                              const float* __restrict__ accums,
                                              const float* __restrict__ temp,
                                              float* __restrict__ out) {
    const int bx = blockIdx.x;                   // 0..127
    const int ci = (bx & 7) * 16 + (bx >> 3);    // bijective; XCD j -> rows [32j,32j+32)
    const int h  = blockIdx.y;
    const int b  = blockIdx.z;
    const int t  = threadIdx.x;
    const int bh = b * NHEAD + h;
    __shared__ float l[256];
    __shared__ float a[256];
    {
        int i = t >> 4, j = t & 15;
        float dsum = 0.0f, q2 = 0.0f, k2 = 0.0f;
        #pragma unroll
        for (int st = 0; st < NSTRIPE; st++) {
            dsum += accums[st * ACCSZ + bh * 256 + t];
            q2   += accums[st * ACCSZ + 2048 + bh * 16 + i];
            k2   += accums[st * ACCSZ + 2176 + bh * 16 + j];
        }
        float qn = fmaxf(sqrtf(q2), 1e-12f);
        float kn = fmaxf(sqrtf(k2), 1e-12f);
        float logit = dsum / (qn * kn) * temp[h];
        l[t] = logit;
        __syncthreads();
        float mx = -1e30f;
        #pragma unroll
        for (int jj = 0; jj < 16; jj++) mx = fmaxf(mx, l[i * 16 + jj]);
        float sum = 0.0f;
        #pragma unroll
        for (int jj = 0; jj < 16; jj++) sum += expf(l[i * 16 + jj] - mx);
        a[t] = expf(logit - mx) / sum;   // a[m*16 + d]
        __syncthreads();
    }

    const int L  = t & 63;
    const int wv = t >> 6;
    const int m  = L & 15;       // A row / D col-group base
    const int kg = L >> 4;       // K-quadrant: 0,1 = hi, 2,3 = lo

    // A-frag (hoisted; same for all 8 s-chunks)
    bf16x8 af;
    #pragma unroll
    for (int j = 0; j < 8; j++) {
        float v = a[m * 16 + (kg & 1) * 8 + j];
        bf16 hv = (bf16)v;
        af[j] = (kg < 2) ? hv : (bf16)(v - (float)hv);
    }

    const bf16* kvb = kvT + ((size_t)b * NS) * 64 + h * DH + (kg & 1) * 8;
    #pragma unroll
    for (int ch = 0; ch < 8; ch++) {
        const int s0 = ci * 512 + wv * 128 + ch * 16;
        bf16x8 kb = *(const bf16x8*)(kvb + (size_t)(s0 + m) * 64);   // 16B aligned
        f32x4 acc = {0.0f, 0.0f, 0.0f, 0.0f};
        acc = __builtin_amdgcn_mfma_f32_16x16x32_bf16(af, kb, acc, 0, 0, 0);
        #pragma unroll
        for (int r = 0; r < 4; r++)
            out[(((size_t)(b * NC + h * DH + kg * 4 + r)) << 16) + s0 + m] = acc[r];
    }
}

extern "C" void kernel_launch(void* const* d_in, const int* in_sizes, int n_in,
                              void* d_out, int out_size, void* d_ws, size_t ws_size,
                              hipStream_t stream) {
    const float* clone = (const float*)d_in[0];
    const float* x     = (const float*)d_in[1];
    const float* u     = (const float*)d_in[2];
    const float* v     = (const float*)d_in[3];
    const float* wgt   = (const float*)d_in[4];
    const float* temp  = (const float*)d_in[5];
    float* out = (float*)d_out;

    char* ws = (char*)d_ws;
    bf16*  cext   = (bf16*) (ws + OFF_CEXT);
    bf16*  kvT    = (bf16*) (ws + OFF_KV);
    bf16*  wpk    = (bf16*) (ws + OFF_WPK);
    float* accums = (float*)(ws + OFF_ACC);

    static bool attr_set = false;
    if (!attr_set) {
        hipFuncSetAttribute((const void*)k1_conv,
                            hipFuncAttributeMaxDynamicSharedMemorySize, 78336);
        attr_set = true;
    }

    k0w<<<90, 256, 0, stream>>>(wgt, wpk, accums);
    k1_conv<<<dim3(5, 43, 2), 256, 78336, stream>>>(clone, wpk, cext);
    k2_gd<<<dim3(1024, 1, 2), 256, 0, stream>>>(u, v, x, cext, kvT, accums);
    k5_out<<<dim3(128, 4, 2), 256, 0, stream>>>(kvT, accums, temp, out);
}

// Round 12
// 156.650 us; speedup vs baseline: 1.1040x; 1.0064x over previous
//
#include <hip/hip_runtime.h>

typedef __bf16 bf16;
typedef __bf16 bf16x4 __attribute__((ext_vector_type(4)));
typedef __bf16 bf16x8 __attribute__((ext_vector_type(8)));
typedef float  f32x2  __attribute__((ext_vector_type(2)));
typedef float  f32x4  __attribute__((ext_vector_type(4)));
typedef float  f32x16 __attribute__((ext_vector_type(16)));

#define HH 256
#define WW 256
#define NB 2
#define NC 64
#define NS 65536
#define EX 258      // extended conv grid: real coords -1..256, stored +1
#define NHEAD 4
#define DH 16
#define NSTRIPE 8
#define ACCSZ 2304  // per stripe: dots 2048 + qss 128 + kss 128

// ws layout (bytes)
#define OFF_CEXT   0ul                 // 2*258*258*64*2 = 17040384
#define OFF_KV     17040384ul          // kvT [b][s][c] bf16: 2*65536*64*2 = 16777216
#define OFF_WPK    33817600ul          // 73728
#define OFF_ACC    33891328ul          // 8*2304*4 = 73728

// ---------------- K0w: pack weights to A-frag layout + zero accums ---------
__global__ void k0w(const float* __restrict__ wgt, bf16* __restrict__ wpk,
                    float* __restrict__ accums) {
    int t = blockIdx.x * 256 + threadIdx.x;
    if (t < 9 * 2 * 4 * 64) {
        int L   = t & 63;
        int mtg = (t >> 6) & 3;
        int kc  = (t >> 8) & 1;
        int tap = t >> 9;
        int o  = mtg * 16 + (L & 15);
        int cb = kc * 32 + (L >> 4) * 8;
        bf16x8 vv;
        #pragma unroll
        for (int j = 0; j < 8; j++)
            vv[j] = (bf16)wgt[(o * 64 + (cb + j)) * 9 + tap];
        *(bf16x8*)(wpk + t * 8) = vv;
    }
    int z = t - 9 * 2 * 4 * 64;
    if (z >= 0 && z < NSTRIPE * ACCSZ) accums[z] = 0.0f;
}

// ---------------- K1: 3x3 conv (R8-verified: 4 waves, 6-row tile) ----------
__global__ __launch_bounds__(256, 2) void k1_conv(const float* __restrict__ clone,
                                                  const bf16* __restrict__ wpk,
                                                  bf16* __restrict__ cext) {
    const int Xt = blockIdx.x;   // 0..4
    const int Yt = blockIdx.y;   // 0..42  (43*6 = 258 exactly)
    const int b  = blockIdx.z;
    const int t  = threadIdx.x;
    const int L  = t & 63;
    const int wv = t >> 6;
    const int mpair = wv >> 1;
    const int npair = wv & 1;

    extern __shared__ bf16 tile[];       // [8 rows][68 cols][c pitch 72]

    bf16x8 afrag[2][9][2];
    #pragma unroll
    for (int mt = 0; mt < 2; mt++)
        #pragma unroll
        for (int tap = 0; tap < 9; tap++)
            #pragma unroll
            for (int kc = 0; kc < 2; kc++) {
                int idx = ((tap * 2 + kc) * 4 + (mpair * 2 + mt)) * 64 + L;
                afrag[mt][tap][kc] = *(const bf16x8*)(wpk + idx * 8);
            }

    for (int u = t; u < 2176; u += 256) {
        int xq = u % 17;
        int rc = u / 17;
        int cg = rc & 15;
        int r  = rc >> 4;
        int y  = Yt * 6 - 2 + r;
        int xg0 = Xt * 64 - 4 + xq * 4;
        int c0 = cg * 4;
        f32x4 f[4];
        bool yin = (y >= 0) && (y < HH);
        if (yin && xg0 >= 0 && xg0 + 3 < WW) {
            #pragma unroll
            for (int i = 0; i < 4; i++)
                f[i] = *(const f32x4*)(clone + ((size_t)(b * NC + c0 + i) * HH + y) * WW + xg0);
        } else {
            #pragma unroll
            for (int i = 0; i < 4; i++)
                #pragma unroll
                for (int e = 0; e < 4; e++) {
                    int xg = xg0 + e;
                    f[i][e] = (yin && xg >= 0 && xg < WW)
                            ? clone[((size_t)(b * NC + c0 + i) * HH + y) * WW + xg] : 0.0f;
                }
        }
        #pragma unroll
        for (int e = 0; e < 4; e++) {
            bf16x4 h;
            #pragma unroll
            for (int i = 0; i < 4; i++) h[i] = (bf16)f[i][e];
            *(bf16x4*)(tile + (r * 68 + xq * 4 + e) * 72 + c0) = h;
        }
    }
    __syncthreads();

    const int nbase = Xt * 64 + npair * 32;
    const f32x4 zero4 = {0.0f, 0.0f, 0.0f, 0.0f};
    for (int Yi = 0; Yi < 6; Yi++) {
        f32x4 acc[2][2];
        acc[0][0] = zero4; acc[0][1] = zero4; acc[1][0] = zero4; acc[1][1] = zero4;
        #pragma unroll
        for (int tap = 0; tap < 9; tap++) {
            const int ky = tap / 3 - 1;
            const int kx = tap % 3 - 1;
            const int r = Yi + 1 + ky;
            #pragma unroll
            for (int kc = 0; kc < 2; kc++) {
                const int cb = kc * 32 + (L >> 4) * 8;
                #pragma unroll
                for (int nt = 0; nt < 2; nt++) {
                    if (nbase + nt * 16 < EX) {   // wave-uniform skip of dead N-tiles
                        const int col = npair * 32 + nt * 16 + (L & 15) + kx + 3;
                        bf16x8 bfrag = *(const bf16x8*)(tile + (r * 68 + col) * 72 + cb);
                        #pragma unroll
                        for (int mt = 0; mt < 2; mt++)
                            acc[mt][nt] = __builtin_amdgcn_mfma_f32_16x16x32_bf16(
                                afrag[mt][tap][kc], bfrag, acc[mt][nt], 0, 0, 0);
                    }
                }
            }
        }
        int Yp = Yt * 6 + Yi;
        #pragma unroll
        for (int mt = 0; mt < 2; mt++)
            #pragma unroll
            for (int nt = 0; nt < 2; nt++) {
                int Xp = Xt * 64 + npair * 32 + nt * 16 + (L & 15);
                if (Xp < EX) {
                    int o = mpair * 32 + mt * 16 + (L >> 4) * 4;
                    bf16x4 st;
                    #pragma unroll
                    for (int rg = 0; rg < 4; rg++) st[rg] = (bf16)acc[mt][nt][rg];
                    *(bf16x4*)(cext + ((((size_t)b * EX + Yp) * EX + Xp) << 6) + o) = st;
                }
            }
    }
}

// ---------------- K2: fused gather + dots, 64-px strips (R8 verified) ------
__global__ __launch_bounds__(256) void k2_gd(const float* __restrict__ uu,
                                             const float* __restrict__ vv,
                                             const float* __restrict__ x,
                                             const bf16* __restrict__ cext,
                                             bf16* __restrict__ kvT,
                                             float* __restrict__ accums) {
    const int bx = blockIdx.x;                     // 0..1023
    const int b  = blockIdx.z;
    const int strip = (bx & 7) * 128 + (bx >> 3);  // bijective (1024 % 8 == 0)
    const int t = threadIdx.x;
    const int px = t >> 2;                         // 0..63
    const int q4 = t & 3;
    const int hw = strip * 64 + px;
    const int idx = b * NS + hw;
    const int hy = hw >> 8;
    const int wx = hw & 255;

    __shared__ bf16 tile[64][68];                  // [s_local][ch], pitch 68

    // ---- gather phase (verified algebra) ----
    float fv = vv[idx];
    float fu = uu[idx];
    float py_f = (float)hy + fv;
    float px_f = (float)wx + fu;
    float fy = floorf(py_f);
    float fx = floorf(px_f);
    float ay = py_f - fy;
    float ax = px_f - fx;
    int ys = (int)fy + 1;
    int xs = (int)fx + 1;
    float w00 = (1.0f - ay) * (1.0f - ax);
    float w01 = (1.0f - ay) * ax;
    float w10 = ay * (1.0f - ax);
    float w11 = ay * ax;
    bool y0i = (ys >= 0) && (ys < EX);
    bool y1i = (ys + 1 >= 0) && (ys + 1 < EX);
    bool x0i = (xs >= 0) && (xs < EX);
    bool x1i = (xs + 1 >= 0) && (xs + 1 < EX);
    if (!y0i) { w00 = 0.0f; w01 = 0.0f; }
    if (!y1i) { w10 = 0.0f; w11 = 0.0f; }
    if (!x0i) { w00 = 0.0f; w10 = 0.0f; }
    if (!x1i) { w01 = 0.0f; w11 = 0.0f; }
    int y0c = ys < 0 ? 0 : (ys > EX - 1 ? EX - 1 : ys);
    int y1c = ys + 1 < 0 ? 0 : (ys + 1 > EX - 1 ? EX - 1 : ys + 1);
    int x0c = xs < 0 ? 0 : (xs > EX - 1 ? EX - 1 : xs);
    int x1c = xs + 1 < 0 ? 0 : (xs + 1 > EX - 1 ? EX - 1 : xs + 1);
    const bf16* pb = cext + (((size_t)b * EX * EX) << 6);
    size_t i00 = ((size_t)(y0c * EX + x0c)) << 6;
    size_t i01 = ((size_t)(y0c * EX + x1c)) << 6;
    size_t i10 = ((size_t)(y1c * EX + x0c)) << 6;
    size_t i11 = ((size_t)(y1c * EX + x1c)) << 6;
    const int c0 = q4 * 16;
    bf16* kvp = kvT + ((size_t)(b * NS + hw)) * 64 + c0;   // 16B-aligned
    #pragma unroll
    for (int g = 0; g < 2; g++) {
        int cg = c0 + g * 8;
        bf16x8 c00 = *(const bf16x8*)(pb + i00 + cg);
        bf16x8 c01 = *(const bf16x8*)(pb + i01 + cg);
        bf16x8 c10 = *(const bf16x8*)(pb + i10 + cg);
        bf16x8 c11 = *(const bf16x8*)(pb + i11 + cg);
        bf16x4 lo, hi;
        bf16x8 sv;
        #pragma unroll
        for (int j = 0; j < 8; j++) {
            float val = w00 * (float)c00[j] + w01 * (float)c01[j]
                      + w10 * (float)c10[j] + w11 * (float)c11[j];
            bf16 hv = (bf16)val;
            sv[j] = hv;
            if (j < 4) lo[j] = hv; else hi[j - 4] = hv;
        }
        *(bf16x8*)(kvp + g * 8) = sv;                      // dense 16B store
        *(bf16x4*)(&tile[px][cg])     = lo;
        *(bf16x4*)(&tile[px][cg + 4]) = hi;
    }
    __syncthreads();

    // ---- dots phase: wave = head (2 MFMA k-iters over 64 s) ----
    const int L  = t & 63;
    const int h  = t >> 6;
    const int row = L & 15;
    const int kg  = L >> 4;
    const int bh = b * NHEAD + h;
    const float* qb = x + ((size_t)(b * NC + h * DH + row)) * NS + strip * 64;
    f32x4 acc = {0.0f, 0.0f, 0.0f, 0.0f};
    float qp = 0.0f, kp = 0.0f;
    #pragma unroll
    for (int it = 0; it < 2; it++) {
        const int s = it * 32 + kg * 8;
        f32x4 q0 = *(const f32x4*)(qb + s);
        f32x4 q1 = *(const f32x4*)(qb + s + 4);
        bf16x8 qa, ka;
        #pragma unroll
        for (int j = 0; j < 4; j++) {
            qa[j]     = (bf16)q0[j];
            qa[j + 4] = (bf16)q1[j];
        }
        #pragma unroll
        for (int j = 0; j < 8; j++) ka[j] = tile[s + j][h * DH + row];
        qp += q0[0]*q0[0] + q0[1]*q0[1] + q0[2]*q0[2] + q0[3]*q0[3]
            + q1[0]*q1[0] + q1[1]*q1[1] + q1[2]*q1[2] + q1[3]*q1[3];
        #pragma unroll
        for (int j = 0; j < 8; j++) {
            float kf = (float)ka[j];
            kp += kf * kf;
        }
        acc = __builtin_amdgcn_mfma_f32_16x16x32_bf16(qa, ka, acc, 0, 0, 0);
    }
    float* astripe = accums + (bx & 7) * ACCSZ;
    #pragma unroll
    for (int rg = 0; rg < 4; rg++)
        atomicAdd(astripe + bh * 256 + (kg * 4 + rg) * 16 + row, acc[rg]);
    qp += __shfl_xor(qp, 16); qp += __shfl_xor(qp, 32);
    kp += __shfl_xor(kp, 16); kp += __shfl_xor(kp, 32);
    if (kg == 0) {
        atomicAdd(astripe + 2048 + bh * 16 + row, qp);
        atomicAdd(astripe + 2176 + bh * 16 + row, kp);
    }
}

// ---------------- K5: softmax + out = attn @ kv via 32x32x16 MFMA ----------
// hi/lo precision split packed into M (rows 0..15 = attn_hi, 16..31 = attn_lo,
// K=16 = d_in exactly). D layout (m74/m101-verified): col=lane&31,
// row=(reg&3)+8*(reg>>2)+4*(lane>>5) -> rows r and r+16 are regs reg, reg+8
// of the SAME lane: hi+lo recombine = free in-lane add. Stores: 32 lanes
// contiguous in s = 128-B segments (2x the 16x16 version). Per 32-px chunk:
// 1x16B load + 1 MFMA + 8 add + 8 store (vs 2 loads + 2 MFMA + 8 store).
__global__ __launch_bounds__(256) void k5_out(const bf16* __restrict__ kvT,
                                              const float* __restrict__ accums,
                                              const float* __restrict__ temp,
                                              float* __restrict__ out) {
    const int bx = blockIdx.x;                   // 0..127
    const int ci = (bx & 7) * 16 + (bx >> 3);    // bijective; XCD-aligned with k2 writes
    const int h  = blockIdx.y;
    const int b  = blockIdx.z;
    const int t  = threadIdx.x;
    const int bh = b * NHEAD + h;
    __shared__ float l[256];
    __shared__ float a[256];
    {
        int i = t >> 4, j = t & 15;
        float dsum = 0.0f, q2 = 0.0f, k2 = 0.0f;
        #pragma unroll
        for (int st = 0; st < NSTRIPE; st++) {
            dsum += accums[st * ACCSZ + bh * 256 + t];
            q2   += accums[st * ACCSZ + 2048 + bh * 16 + i];
            k2   += accums[st * ACCSZ + 2176 + bh * 16 + j];
        }
        float qn = fmaxf(sqrtf(q2), 1e-12f);
        float kn = fmaxf(sqrtf(k2), 1e-12f);
        float logit = dsum / (qn * kn) * temp[h];
        l[t] = logit;
        __syncthreads();
        float mx = -1e30f;
        #pragma unroll
        for (int jj = 0; jj < 16; jj++) mx = fmaxf(mx, l[i * 16 + jj]);
        float sum = 0.0f;
        #pragma unroll
        for (int jj = 0; jj < 16; jj++) sum += expf(l[i * 16 + jj] - mx);
        a[t] = expf(logit - mx) / sum;   // a[c*16 + d]
        __syncthreads();
    }

    const int L   = t & 63;
    const int wv  = t >> 6;
    const int r31 = L & 31;      // A row (c for hi, c+16 for lo) / B,D col = s
    const int h5  = L >> 5;      // K half: d_in = h5*8 + j

    // A-frag hoisted: rows 0..15 = bf16(attn), rows 16..31 = bf16(attn - hi)
    bf16x8 af;
    #pragma unroll
    for (int j = 0; j < 8; j++) {
        if (r31 < 16) {
            af[j] = (bf16)a[r31 * 16 + h5 * 8 + j];
        } else {
            float v  = a[(r31 - 16) * 16 + h5 * 8 + j];
            bf16 hv = (bf16)v;
            af[j] = (bf16)(v - (float)hv);
        }
    }

    const bf16* kvb = kvT + ((size_t)b * NS) * 64 + h * DH + h5 * 8;
    #pragma unroll
    for (int ch = 0; ch < 4; ch++) {
        const int s0 = ci * 512 + wv * 128 + ch * 32;
        bf16x8 kb = *(const bf16x8*)(kvb + (size_t)(s0 + r31) * 64);   // 16B aligned
        f32x16 acc;
        #pragma unroll
        for (int z = 0; z < 16; z++) acc[z] = 0.0f;
        acc = __builtin_amdgcn_mfma_f32_32x32x16_bf16(af, kb, acc, 0, 0, 0);
        #pragma unroll
        for (int reg = 0; reg < 8; reg++) {
            const int orow = (reg & 3) + 8 * (reg >> 2) + 4 * h5;   // 0..15
            out[(((size_t)(b * NC + h * DH + orow)) << 16) + s0 + r31]
                = acc[reg] + acc[reg + 8];                          // hi + lo
        }
    }
}

extern "C" void kernel_launch(void* const* d_in, const int* in_sizes, int n_in,
                              void* d_out, int out_size, void* d_ws, size_t ws_size,
                              hipStream_t stream) {
    const float* clone = (const float*)d_in[0];
    const float* x     = (const float*)d_in[1];
    const float* u     = (const float*)d_in[2];
    const float* v     = (const float*)d_in[3];
    const float* wgt   = (const float*)d_in[4];
    const float* temp  = (const float*)d_in[5];
    float* out = (float*)d_out;

    char* ws = (char*)d_ws;
    bf16*  cext   = (bf16*) (ws + OFF_CEXT);
    bf16*  kvT    = (bf16*) (ws + OFF_KV);
    bf16*  wpk    = (bf16*) (ws + OFF_WPK);
    float* accums = (float*)(ws + OFF_ACC);

    static bool attr_set = false;
    if (!attr_set) {
        hipFuncSetAttribute((const void*)k1_conv,
                            hipFuncAttributeMaxDynamicSharedMemorySize, 78336);
        attr_set = true;
    }

    k0w<<<90, 256, 0, stream>>>(wgt, wpk, accums);
    k1_conv<<<dim3(5, 43, 2), 256, 78336, stream>>>(clone, wpk, cext);
    k2_gd<<<dim3(1024, 1, 2), 256, 0, stream>>>(u, v, x, cext, kvT, accums);
    k5_out<<<dim3(128, 4, 2), 256, 0, stream>>>(kvT, accums, temp, out);
}